// Round 8
// baseline (270.758 us; speedup 1.0000x reference)
//
#include <hip/hip_runtime.h>

// TripletAngularMarginLoss: bs=16384, d=64 (== number of classes)
// out = mean(relu(0.5 + ap - an)) + mean(relu(0.8-ap)) + mean(relu(an-0.4)) + CE
// ap[i] = min_{t[j]==t[i]} cos(x_i,x_j), an[i] = max_{t[j]!=t[i]} cos(x_i,x_j)
//
// R7 conclusion: mine is VALU-ISSUE-bound (106us invariant to barriers/
// occupancy/spills; VALUBusy ~70%). R8: counting-sort rows by class so the
// pos/neg test is wave-uniform per 16-col tile; dominant path = 1 v_max/elem
// instead of cmp+2*cndmask+min+max. Loss terms are means -> permutation
// invariant; only mine works in sorted space (CE stays in original order).

#define N_ROWS 16384
#define N_DIM 64
#define N_CLS 64

typedef __attribute__((ext_vector_type(8))) short bf16x8;
typedef __attribute__((ext_vector_type(8))) unsigned short ushort8;
typedef __attribute__((ext_vector_type(4))) float f32x4;

__device__ inline unsigned short f2bf(float f) {
  unsigned u = __float_as_uint(f);
  unsigned r = u + 0x7fffu + ((u >> 16) & 1u);   // round-to-nearest-even
  return (unsigned short)(r >> 16);
}

// order-preserving float->uint encoding for atomicMin/atomicMax
__device__ inline unsigned enc_key(float f) {
  unsigned u = __float_as_uint(f);
  return (u & 0x80000000u) ? ~u : (u | 0x80000000u);
}
__device__ inline float dec_key(unsigned k) {
  unsigned u = (k & 0x80000000u) ? (k ^ 0x80000000u) : ~k;
  return __uint_as_float(u);
}

// async global->LDS DMA, 16B per lane, dest = lds_base + lane*16 (linear)
__device__ inline void g2lds16(const void* g, void* l) {
  __builtin_amdgcn_global_load_lds(
      (const __attribute__((address_space(1))) void*)g,
      (__attribute__((address_space(3))) void*)l, 16, 0, 0);
}

// ---------------- Kernel A: normalize rows, bf16 copy, per-row CE, histogram -
__global__ void prep_kernel(const float* __restrict__ x, const int* __restrict__ tgt,
                            unsigned short* __restrict__ xb, float* __restrict__ ce_row,
                            unsigned* __restrict__ mp_key, unsigned* __restrict__ mn_key,
                            unsigned* __restrict__ hist, float* __restrict__ out) {
  const int row  = blockIdx.x * 4 + (threadIdx.x >> 6);
  const int lane = threadIdx.x & 63;
  float v  = x[row * N_DIM + lane];
  float ss = v * v;
#pragma unroll
  for (int s = 1; s < 64; s <<= 1) ss += __shfl_xor(ss, s, 64);
  float xn = v * rsqrtf(ss);
  xb[row * N_DIM + lane] = f2bf(xn);

  // log-softmax over the 64 normalized features
  float mx = xn;
#pragma unroll
  for (int s = 1; s < 64; s <<= 1) mx = fmaxf(mx, __shfl_xor(mx, s, 64));
  float e  = __expf(xn - mx);
  float se = e;
#pragma unroll
  for (int s = 1; s < 64; s <<= 1) se += __shfl_xor(se, s, 64);
  float lse = mx + __logf(se);
  int   t   = tgt[row];                 // wave-uniform
  float xt  = __shfl(xn, t, 64);
  if (lane == 0) {
    ce_row[row] = lse - xt;
    mp_key[row] = 0xFFFFFFFFu;          // +inf key for atomicMin
    mn_key[row] = 0u;                   // -inf key for atomicMax
    atomicAdd(&hist[t], 1u);            // class histogram (hist pre-zeroed)
  }
  if (blockIdx.x == 0 && threadIdx.x == 0) out[0] = 0.f;
}

// ---------------- Kernel A2: 64-entry exclusive scan -> scatter cursors ------
__global__ void scan_kernel(const unsigned* __restrict__ hist, unsigned* __restrict__ cursor) {
  if (threadIdx.x == 0) {
    unsigned run = 0;
    for (int c = 0; c < N_CLS; ++c) { cursor[c] = run; run += hist[c]; }
  }
}

// ---------------- Kernel A3: scatter rows into class-sorted order ------------
// 8 lanes per row (16B each, coalesced); lane0 of each group takes the cursor.
__global__ void scatter_kernel(const unsigned short* __restrict__ xb, const int* __restrict__ tgt,
                               unsigned* __restrict__ cursor, unsigned short* __restrict__ xbs,
                               unsigned short* __restrict__ tgs) {
  const int lane = threadIdx.x & 63;
  const int sub  = lane & 7;
  const int row  = blockIdx.x * 32 + (threadIdx.x >> 6) * 8 + (lane >> 3);
  const int c    = tgt[row];
  int dst = 0;
  if (sub == 0) dst = (int)atomicAdd(&cursor[c], 1u);
  dst = __shfl(dst, lane & 56, 64);     // broadcast from the group leader
  ((ushort8*)xbs)[dst * 8 + sub] = ((const ushort8*)xb)[row * 8 + sub];
  if (sub == 0) tgs[dst] = (unsigned short)c;
}

// ---------------- Kernel B: MFMA similarity tiles + hard mining (sorted) -----
// grid = 128 i-blocks * 16 j-splits = 2048 blocks of 256 threads (4 waves).
// Phase = 4 tiles staged via global_load_lds (double-buffered, XOR-swizzled),
// unroll-1 j4 loop (R6 lesson: full unroll explodes pressure).
// Sorted rows: wave's 32 rows span [clo,chi]; tile's 16 cols span [tlo,thi]
// (endpoints suffice - sorted). Disjoint -> 1 v_max/elem; all-same-class ->
// 1 v_min/elem; boundary (rare) -> full 5-op path.
__global__ __launch_bounds__(256, 8)
void mine_kernel(const unsigned short* __restrict__ xbs, const unsigned short* __restrict__ tgs,
                 unsigned* __restrict__ mp_key, unsigned* __restrict__ mn_key) {
  __shared__ unsigned short Bt[2][4][1024];   // 2 bufs x 4 tiles x 2KB, swizzled
  __shared__ unsigned short tjl[N_ROWS / 16]; // 2KB: classes of this j-range

  const int lane    = threadIdx.x & 63;
  const int wv      = threadIdx.x >> 6;
  const int iblk    = blockIdx.x >> 4;
  const int jspl    = blockIdx.x & 15;
  const int rowbase = iblk * 128 + wv * 32;
  const int m = lane & 15, q = lane >> 4;
  const int jbase = jspl * (N_ROWS / 16);

  // A fragments: lane holds row (rowbase+tr*16+m), k = q*8..q*8+7 (+32 for ks=1)
  bf16x8 a[2][2];
#pragma unroll
  for (int tr = 0; tr < 2; ++tr) {
    const unsigned short* p = xbs + (rowbase + tr * 16 + m) * N_DIM + q * 8;
    a[tr][0] = *(const bf16x8*)(p);
    a[tr][1] = *(const bf16x8*)(p + 32);
  }
  // packed classes of the C/D rows this lane owns (row = tr*16+q*4+r), 8b each
  unsigned tip[2];
#pragma unroll
  for (int tr = 0; tr < 2; ++tr) {
    unsigned vv = 0;
#pragma unroll
    for (int r = 0; r < 4; ++r)
      vv |= ((unsigned)tgs[rowbase + tr * 16 + q * 4 + r] & 0xffu) << (8 * r);
    tip[tr] = vv;
  }
  // wave's class range (rows sorted -> endpoints suffice), wave-uniform SGPRs
  const int clo = __builtin_amdgcn_readfirstlane((int)tgs[rowbase]);
  const int chi = __builtin_amdgcn_readfirstlane((int)tgs[rowbase + 31]);

  float mp[8], mn[8];
#pragma unroll
  for (int k = 0; k < 8; ++k) { mp[k] = __builtin_inff(); mn[k] = -__builtin_inff(); }

  // preload j-range classes into LDS
  for (int k = threadIdx.x; k < N_ROWS / 16; k += 256) tjl[k] = tgs[jbase + k];

  // Staging (inverse-swizzled global source, linear LDS dest):
  const unsigned short* src0 =
      xbs + (jbase + (lane >> 3)) * N_DIM + (((lane & 7) ^ ((lane >> 3) & 7)) * 8);

  {  // prologue: stage phase 0 (tiles 0..3) into buffer 0
    const unsigned short* s = src0 + (wv * 16) * N_DIM;
    g2lds16(s,             (unsigned short*)&Bt[0][wv][0] + lane * 8);
    g2lds16(s + 8 * N_DIM, (unsigned short*)&Bt[0][wv][0] + 512 + lane * 8);
  }
  __syncthreads();

  // swizzled fragment-read byte offsets (constant per lane)
  const int roff0 = m * 128 + ((q * 16) ^ ((m & 7) << 4));
  const int roff1 = m * 128 + (((64) + q * 16) ^ ((m & 7) << 4));

  for (int ph = 0; ph < 16; ++ph) {
    const int pb = ph & 1;
    if (ph < 15) {                      // stage phase ph+1 into the other buffer
      const unsigned short* s = src0 + ((ph + 1) * 64 + wv * 16) * N_DIM;
      g2lds16(s,             (unsigned short*)&Bt[pb ^ 1][wv][0] + lane * 8);
      g2lds16(s + 8 * N_DIM, (unsigned short*)&Bt[pb ^ 1][wv][0] + 512 + lane * 8);
    }
#pragma unroll 1
    for (int j4 = 0; j4 < 4; ++j4) {
      const int jc = ph * 4 + j4;
      const char* bb = (const char*)&Bt[pb][j4][0];
      const bf16x8 cb0 = *(const bf16x8*)(bb + roff0);
      const bf16x8 cb1 = *(const bf16x8*)(bb + roff1);
      const int tlo = __builtin_amdgcn_readfirstlane((int)tjl[jc * 16]);
      const int thi = __builtin_amdgcn_readfirstlane((int)tjl[jc * 16 + 15]);

      f32x4 acc0 = {0.f, 0.f, 0.f, 0.f}, acc1 = {0.f, 0.f, 0.f, 0.f};
      acc0 = __builtin_amdgcn_mfma_f32_16x16x32_bf16(a[0][0], cb0, acc0, 0, 0, 0);
      acc0 = __builtin_amdgcn_mfma_f32_16x16x32_bf16(a[0][1], cb1, acc0, 0, 0, 0);
      acc1 = __builtin_amdgcn_mfma_f32_16x16x32_bf16(a[1][0], cb0, acc1, 0, 0, 0);
      acc1 = __builtin_amdgcn_mfma_f32_16x16x32_bf16(a[1][1], cb1, acc1, 0, 0, 0);

      if (thi < clo || tlo > chi) {
        // all 16 cols negative for all 32 rows: 1 v_max per element
#pragma unroll
        for (int r = 0; r < 4; ++r) {
          mn[r]     = fmaxf(mn[r],     acc0[r]);
          mn[4 + r] = fmaxf(mn[4 + r], acc1[r]);
        }
      } else if (clo == chi && tlo == thi && tlo == clo) {
        // all 16 cols positive for all 32 rows: 1 v_min per element
#pragma unroll
        for (int r = 0; r < 4; ++r) {
          mp[r]     = fminf(mp[r],     acc0[r]);
          mp[4 + r] = fminf(mp[4 + r], acc1[r]);
        }
      } else {
        // boundary tile (rare): full per-element compare path
        const unsigned ctj = (unsigned)tjl[jc * 16 + m] & 0xffu;
#pragma unroll
        for (int tr = 0; tr < 2; ++tr) {
          const f32x4 ac = tr ? acc1 : acc0;
#pragma unroll
          for (int r = 0; r < 4; ++r) {
            const bool  pos = (((tip[tr] >> (8 * r)) & 0xffu) == ctj);
            const float d   = ac[r];
            const int   k   = tr * 4 + r;
            mp[k] = fminf(mp[k], pos ? d : __builtin_inff());
            mn[k] = fmaxf(mn[k], pos ? -__builtin_inff() : d);
          }
        }
      }
    }
    __syncthreads();   // one vmcnt-drain + barrier per 4-tile phase
  }

  // reduce across the 16 lanes (m = 0..15) inside each q-group
#pragma unroll
  for (int s = 1; s < 16; s <<= 1) {
#pragma unroll
    for (int k = 0; k < 8; ++k) {
      mp[k] = fminf(mp[k], __shfl_xor(mp[k], s, 64));
      mn[k] = fmaxf(mn[k], __shfl_xor(mn[k], s, 64));
    }
  }
  if (m == 0) {
#pragma unroll
    for (int tr = 0; tr < 2; ++tr)
#pragma unroll
      for (int r = 0; r < 4; ++r) {
        const int row = rowbase + tr * 16 + q * 4 + r;   // sorted index - fine
        atomicMin(&mp_key[row], enc_key(mp[tr * 4 + r]));
        atomicMax(&mn_key[row], enc_key(mn[tr * 4 + r]));
      }
  }
}

// ---------------- Kernel C: final reduction (8 blocks, float atomicAdd) ------
__global__ void finalize_kernel(const unsigned* __restrict__ mp_key, const unsigned* __restrict__ mn_key,
                                const float* __restrict__ ce_row, float* __restrict__ out) {
  __shared__ float red[16];
  float s = 0.f;
#pragma unroll
  for (int it = 0; it < 2; ++it) {
    const int r = it * 8192 + blockIdx.x * 1024 + threadIdx.x;
    float ap = dec_key(mp_key[r]);
    float an = dec_key(mn_key[r]);
    s += fmaxf(0.5f + ap - an, 0.f) + fmaxf(0.8f - ap, 0.f) +
         fmaxf(an - 0.4f, 0.f) + ce_row[r];
  }
#pragma unroll
  for (int sh = 1; sh < 64; sh <<= 1) s += __shfl_xor(s, sh, 64);
  const int wv = threadIdx.x >> 6;
  if ((threadIdx.x & 63) == 0) red[wv] = s;
  __syncthreads();
  if (threadIdx.x == 0) {
    float t = 0.f;
#pragma unroll
    for (int w = 0; w < 16; ++w) t += red[w];
    atomicAdd(out, t * (1.0f / N_ROWS));
  }
}

extern "C" void kernel_launch(void* const* d_in, const int* in_sizes, int n_in,
                              void* d_out, int out_size, void* d_ws, size_t ws_size,
                              hipStream_t stream) {
  const float* x   = (const float*)d_in[0];
  const int*   tgt = (const int*)d_in[1];
  char* ws = (char*)d_ws;

  unsigned short* xb     = (unsigned short*)ws;                           // 2 MB normalized bf16
  unsigned short* xbs    = (unsigned short*)(ws + (2u << 20));            // 2 MB class-sorted
  unsigned*       mp_key = (unsigned*)(ws + (4u << 20));                  // 64 KB
  unsigned*       mn_key = (unsigned*)(ws + (4u << 20) + (64u << 10));    // 64 KB
  float*          ce_row = (float*)(ws + (4u << 20) + (128u << 10));      // 64 KB
  unsigned short* tgs    = (unsigned short*)(ws + (4u << 20) + (192u << 10)); // 32 KB
  unsigned*       hist   = (unsigned*)(ws + (4u << 20) + (224u << 10));   // 256 B
  unsigned*       cursor = hist + 64;                                     // 256 B
  float*          out    = (float*)d_out;

  hipMemsetAsync(hist, 0, 256, stream);
  prep_kernel<<<N_ROWS / 4, 256, 0, stream>>>(x, tgt, xb, ce_row, mp_key, mn_key, hist, out);
  scan_kernel<<<1, 64, 0, stream>>>(hist, cursor);
  scatter_kernel<<<N_ROWS / 32, 256, 0, stream>>>(xb, tgt, cursor, xbs, tgs);
  mine_kernel<<<(N_ROWS / 128) * 16, 256, 0, stream>>>(xbs, tgs, mp_key, mn_key);
  finalize_kernel<<<8, 1024, 0, stream>>>(mp_key, mn_key, ce_row, out);
}

// Round 9
// 157.270 us; speedup vs baseline: 1.7216x; 1.7216x over previous
//
#include <hip/hip_runtime.h>

// TripletAngularMarginLoss: bs=16384, d=64 (== number of classes)
// out = mean(relu(0.5 + ap - an)) + mean(relu(0.8-ap)) + mean(relu(an-0.4)) + CE
// ap[i] = min_{t[j]==t[i]} cos(x_i,x_j), an[i] = max_{t[j]!=t[i]} cos(x_i,x_j)
//
// R8 conclusion: NOT VALU-issue-bound (VALUBusy -19pts -> dur -5%). The
// structure-invariant ~103us is the __syncthreads vmcnt(0) drain: it waits
// the JUST-ISSUED next-phase DMA every phase, so "prefetch" was synchronous
// staging all along. R9 = T4: counted s_waitcnt vmcnt(2) + raw s_barrier,
// 2-phase-deep DMA pipeline that is never drained in the main loop.

#define N_ROWS 16384
#define N_DIM 64

typedef __attribute__((ext_vector_type(8))) short bf16x8;
typedef __attribute__((ext_vector_type(4))) float f32x4;

__device__ inline unsigned short f2bf(float f) {
  unsigned u = __float_as_uint(f);
  unsigned r = u + 0x7fffu + ((u >> 16) & 1u);   // round-to-nearest-even
  return (unsigned short)(r >> 16);
}

// order-preserving float->uint encoding for atomicMin/atomicMax
__device__ inline unsigned enc_key(float f) {
  unsigned u = __float_as_uint(f);
  return (u & 0x80000000u) ? ~u : (u | 0x80000000u);
}
__device__ inline float dec_key(unsigned k) {
  unsigned u = (k & 0x80000000u) ? (k ^ 0x80000000u) : ~k;
  return __uint_as_float(u);
}

// async global->LDS DMA, 16B per lane, dest = lds_base + lane*16 (linear)
__device__ inline void g2lds16(const void* g, void* l) {
  __builtin_amdgcn_global_load_lds(
      (const __attribute__((address_space(1))) void*)g,
      (__attribute__((address_space(3))) void*)l, 16, 0, 0);
}

// ---------------- Kernel A: normalize rows, emit bf16 copy, per-row CE -------
__global__ void prep_kernel(const float* __restrict__ x, const int* __restrict__ tgt,
                            unsigned short* __restrict__ xb, float* __restrict__ ce_row,
                            unsigned* __restrict__ mp_key, unsigned* __restrict__ mn_key,
                            float* __restrict__ out) {
  const int row  = blockIdx.x * 4 + (threadIdx.x >> 6);
  const int lane = threadIdx.x & 63;
  float v  = x[row * N_DIM + lane];
  float ss = v * v;
#pragma unroll
  for (int s = 1; s < 64; s <<= 1) ss += __shfl_xor(ss, s, 64);
  float xn = v * rsqrtf(ss);
  xb[row * N_DIM + lane] = f2bf(xn);

  float mx = xn;
#pragma unroll
  for (int s = 1; s < 64; s <<= 1) mx = fmaxf(mx, __shfl_xor(mx, s, 64));
  float e  = __expf(xn - mx);
  float se = e;
#pragma unroll
  for (int s = 1; s < 64; s <<= 1) se += __shfl_xor(se, s, 64);
  float lse = mx + __logf(se);
  int   t   = tgt[row];                 // wave-uniform
  float xt  = __shfl(xn, t, 64);
  if (lane == 0) {
    ce_row[row] = lse - xt;
    mp_key[row] = 0xFFFFFFFFu;          // +inf key for atomicMin
    mn_key[row] = 0u;                   // -inf key for atomicMax
  }
  if (blockIdx.x == 0 && threadIdx.x == 0) out[0] = 0.f;
}

// ---------------- Kernel B: MFMA similarity tiles + hard mining --------------
// grid = 128 i-blocks * 16 j-splits = 2048 blocks of 256 threads (4 waves) =
// 8 blocks/CU. Phase = 4 tiles (each wave DMAs one tile = 2 g2lds16).
// T4 pipeline: 2 phases in flight; per phase:
//   compute(ph) -> s_barrier -> stage(ph+2) -> vmcnt(2) -> s_barrier
// vmcnt(2) guarantees ph+1 landed while ph+2's 2 DMAs stay in flight.
// NO vmcnt(0) drain anywhere in the main loop (the R1-R8 invariant stall).
__global__ __launch_bounds__(256, 8)
void mine_kernel(const unsigned short* __restrict__ xb, const int* __restrict__ tgt,
                 unsigned* __restrict__ mp_key, unsigned* __restrict__ mn_key) {
  __shared__ unsigned short Bt[2][4][1024];   // 2 bufs x 4 tiles x 2KB, swizzled
  __shared__ unsigned short tjl[N_ROWS / 16]; // 2KB: targets of this j-range

  const int lane    = threadIdx.x & 63;
  const int wv      = threadIdx.x >> 6;
  const int iblk    = blockIdx.x >> 4;
  const int jspl    = blockIdx.x & 15;
  const int rowbase = iblk * 128 + wv * 32;
  const int m = lane & 15, q = lane >> 4;
  const int jbase = jspl * (N_ROWS / 16);

  // A fragments: lane holds row (rowbase+tr*16+m), k = q*8..q*8+7 (+32 for ks=1)
  bf16x8 a[2][2];
#pragma unroll
  for (int tr = 0; tr < 2; ++tr) {
    const unsigned short* p = xb + (rowbase + tr * 16 + m) * N_DIM + q * 8;
    a[tr][0] = *(const bf16x8*)(p);
    a[tr][1] = *(const bf16x8*)(p + 32);
  }
  int ti[2][4];
#pragma unroll
  for (int tr = 0; tr < 2; ++tr)
#pragma unroll
    for (int r = 0; r < 4; ++r)
      ti[tr][r] = tgt[rowbase + tr * 16 + q * 4 + r];

  float mp[8], mn[8];
#pragma unroll
  for (int k = 0; k < 8; ++k) { mp[k] = __builtin_inff(); mn[k] = -__builtin_inff(); }

  for (int k = threadIdx.x; k < N_ROWS / 16; k += 256)
    tjl[k] = (unsigned short)tgt[jbase + k];

  // Staging (inverse-swizzled global source, linear LDS dest):
  const unsigned short* src0 =
      xb + (jbase + (lane >> 3)) * N_DIM + (((lane & 7) ^ ((lane >> 3) & 7)) * 8);

#define STAGE(P, BUF)                                                            \
  do {                                                                           \
    const unsigned short* s_ = src0 + ((P) * 64 + wv * 16) * N_DIM;              \
    g2lds16(s_,             (unsigned short*)&Bt[(BUF)][wv][0] + lane * 8);      \
    g2lds16(s_ + 8 * N_DIM, (unsigned short*)&Bt[(BUF)][wv][0] + 512 + lane * 8);\
  } while (0)

  // prologue: stage phases 0 and 1; one full drain here (once) also covers tjl
  STAGE(0, 0);
  STAGE(1, 1);
  __syncthreads();

  // swizzled fragment-read byte offsets (constant per lane)
  const int roff0 = m * 128 + ((q * 16) ^ ((m & 7) << 4));
  const int roff1 = m * 128 + (((64) + q * 16) ^ ((m & 7) << 4));

  for (int ph = 0; ph < 16; ++ph) {
    const int pb = ph & 1;
#pragma unroll 1
    for (int j4 = 0; j4 < 4; ++j4) {
      const int jc = ph * 4 + j4;
      const char* bb = (const char*)&Bt[pb][j4][0];
      const bf16x8 cb0 = *(const bf16x8*)(bb + roff0);
      const bf16x8 cb1 = *(const bf16x8*)(bb + roff1);
      const int    ctj = tjl[jc * 16 + m];

#pragma unroll
      for (int tr = 0; tr < 2; ++tr) {
        f32x4 acc = {0.f, 0.f, 0.f, 0.f};
        acc = __builtin_amdgcn_mfma_f32_16x16x32_bf16(a[tr][0], cb0, acc, 0, 0, 0);
        acc = __builtin_amdgcn_mfma_f32_16x16x32_bf16(a[tr][1], cb1, acc, 0, 0, 0);
#pragma unroll
        for (int r = 0; r < 4; ++r) {
          const bool  pos = (ctj == ti[tr][r]);
          const float d   = acc[r];
          const int   k   = tr * 4 + r;
          mp[k] = fminf(mp[k], pos ? d : __builtin_inff());
          mn[k] = fmaxf(mn[k], pos ? -__builtin_inff() : d);
        }
      }
    }
    // all ds_read data consumed by MFMAs above -> safe to hit raw barrier
    __builtin_amdgcn_s_barrier();            // everyone done READING Bt[pb]
    if (ph < 14) {
      STAGE(ph + 2, pb);                     // overwrite freed buffer
      asm volatile("s_waitcnt vmcnt(2)" ::: "memory");  // ph+1 landed; ph+2 flies
      __builtin_amdgcn_sched_barrier(0);
      __builtin_amdgcn_s_barrier();          // publish ph+1 tiles
    } else if (ph == 14) {
      asm volatile("s_waitcnt vmcnt(0)" ::: "memory");  // last phase's 2 DMAs
      __builtin_amdgcn_sched_barrier(0);
      __builtin_amdgcn_s_barrier();
    }
  }

  // reduce across the 16 lanes (m = 0..15) inside each q-group
#pragma unroll
  for (int s = 1; s < 16; s <<= 1) {
#pragma unroll
    for (int k = 0; k < 8; ++k) {
      mp[k] = fminf(mp[k], __shfl_xor(mp[k], s, 64));
      mn[k] = fmaxf(mn[k], __shfl_xor(mn[k], s, 64));
    }
  }
  if (m == 0) {
#pragma unroll
    for (int tr = 0; tr < 2; ++tr)
#pragma unroll
      for (int r = 0; r < 4; ++r) {
        const int row = rowbase + tr * 16 + q * 4 + r;
        atomicMin(&mp_key[row], enc_key(mp[tr * 4 + r]));
        atomicMax(&mn_key[row], enc_key(mn[tr * 4 + r]));
      }
  }
#undef STAGE
}

// ---------------- Kernel C: final reduction (8 blocks, float atomicAdd) ------
__global__ void finalize_kernel(const unsigned* __restrict__ mp_key, const unsigned* __restrict__ mn_key,
                                const float* __restrict__ ce_row, float* __restrict__ out) {
  __shared__ float red[16];
  float s = 0.f;
#pragma unroll
  for (int it = 0; it < 2; ++it) {
    const int r = it * 8192 + blockIdx.x * 1024 + threadIdx.x;
    float ap = dec_key(mp_key[r]);
    float an = dec_key(mn_key[r]);
    s += fmaxf(0.5f + ap - an, 0.f) + fmaxf(0.8f - ap, 0.f) +
         fmaxf(an - 0.4f, 0.f) + ce_row[r];
  }
#pragma unroll
  for (int sh = 1; sh < 64; sh <<= 1) s += __shfl_xor(s, sh, 64);
  const int wv = threadIdx.x >> 6;
  if ((threadIdx.x & 63) == 0) red[wv] = s;
  __syncthreads();
  if (threadIdx.x == 0) {
    float t = 0.f;
#pragma unroll
    for (int w = 0; w < 16; ++w) t += red[w];
    atomicAdd(out, t * (1.0f / N_ROWS));
  }
}

extern "C" void kernel_launch(void* const* d_in, const int* in_sizes, int n_in,
                              void* d_out, int out_size, void* d_ws, size_t ws_size,
                              hipStream_t stream) {
  const float* x   = (const float*)d_in[0];
  const int*   tgt = (const int*)d_in[1];
  char* ws = (char*)d_ws;

  unsigned short* xb     = (unsigned short*)ws;                          // 2 MB bf16 normalized
  unsigned*       mp_key = (unsigned*)(ws + (2u << 20));                 // 64 KB
  unsigned*       mn_key = (unsigned*)(ws + (2u << 20) + (64u << 10));   // 64 KB
  float*          ce_row = (float*)(ws + (2u << 20) + (128u << 10));     // 64 KB
  float*          out    = (float*)d_out;

  prep_kernel<<<N_ROWS / 4, 256, 0, stream>>>(x, tgt, xb, ce_row, mp_key, mn_key, out);
  mine_kernel<<<(N_ROWS / 128) * 16, 256, 0, stream>>>(xb, tgt, mp_key, mn_key);
  finalize_kernel<<<8, 1024, 0, stream>>>(mp_key, mn_key, ce_row, out);
}